// Round 5
// baseline (311.135 us; speedup 1.0000x reference)
//
#include <hip/hip_runtime.h>
#include <hip/hip_bf16.h>

// ---------------------------------------------------------------------------
// Generator_58737972740271.  R18 = R17 + dispatch-count reduction (13 -> 11).
// R17 post-mortem: -77MB HBM made no difference => relation kernels are not
// traffic-bound; time = harness poison fill (~43us, untouchable) + 13 kernel
// dispatch fixed costs + ~110us work.  R18 merges, bit-identically:
//  (1) k_prep + k_bnlin12 -> k_enc0: e1/e2 transposes go inline (raw loads,
//      same float values); prep's 9 remaining weight sets ride along as
//      blocks 512.. of the same dispatch (no dependency between halves).
//  (2) k_bnlin<128,64> + k_dec2 -> k_dectail: BN'd decoder activations are
//      rounded through bf16 (replicating the old Cdec store/load exactly),
//      kept in LDS, and the 64->32->32 tail runs in-block.  Cdec round-trip
//      (8 MB) and one dispatch eliminated.  LDS overlaid: dec weights into
//      dead wt region, cst/hs into dead xst region => 69KB, 2 blk/CU kept.
// ---------------------------------------------------------------------------

typedef __hip_bfloat16 bf16;
typedef unsigned short ushort_t;
typedef float v4f __attribute__((ext_vector_type(4)));
typedef short v8s __attribute__((ext_vector_type(8)));
#define MFMA_BF16 __builtin_amdgcn_mfma_f32_16x16x32_bf16

#define NB 32
#define NN 1024
#define XSTRIDE 72   // padded [n][r] stride (16B-aligned, breaks bank conflicts)

__device__ __forceinline__ float ldin(const void* p, size_t i, int f32){
    return f32 ? ((const float*)p)[i] : __bfloat162float(((const bf16*)p)[i]);
}
__device__ __forceinline__ float bf2f(ushort_t u){
    return __uint_as_float((unsigned)u << 16);
}
__device__ __forceinline__ ushort_t f2bf(float v){
    bf16 h = __float2bfloat16(v);
    ushort_t s; __builtin_memcpy(&s, &h, 2);
    return s;
}
__device__ __forceinline__ void unpack8(uint4 v, float* f){
    f[0] = __uint_as_float(v.x << 16);
    f[1] = __uint_as_float(v.x & 0xffff0000u);
    f[2] = __uint_as_float(v.y << 16);
    f[3] = __uint_as_float(v.y & 0xffff0000u);
    f[4] = __uint_as_float(v.z << 16);
    f[5] = __uint_as_float(v.z & 0xffff0000u);
    f[6] = __uint_as_float(v.w << 16);
    f[7] = __uint_as_float(v.w & 0xffff0000u);
}

__device__ __forceinline__ int detect_dev(const void* inp){
    __shared__ int sflag;
    int t = threadIdx.x;
    if (t < 64){
        unsigned v = ((const unsigned*)inp)[t];
        unsigned long long m = __ballot((v & 0x80008000u) != 0u);
        if (t == 0) sflag = (__popcll(m) > 4) ? 1 : 0;
    }
    __syncthreads();
    return sflag;
}

// ---------------- merged: weight prep + encoder lin/BN/ReLU x2 -------------
// blocks [0,512): bnlin12 (channel n = bx*2 + wave); e1/e2 transposed inline.
// blocks [512,512+9*128): weight conversion (4 f32 sets + 5 MFMA hi/lo sets).
struct PrepArgs {
    const void* w[9];
    int K[9], O[9], off[9];
};

__global__ __launch_bounds__(128) void k_enc0(PrepArgs a, float* __restrict__ wpf,
    ushort_t* __restrict__ whi, ushort_t* __restrict__ wlo,
    const void* __restrict__ xin,
    const void* __restrict__ e1w, const void* __restrict__ b1v,
    const void* __restrict__ g1, const void* __restrict__ bb1,
    const void* __restrict__ e2w, const void* __restrict__ b2v,
    const void* __restrict__ g2, const void* __restrict__ bb2,
    ushort_t* __restrict__ out, const void* __restrict__ detin)
{
    int f32 = detect_dev(detin);
    int t = threadIdx.x;

    if (blockIdx.x >= 512){                 // ---- prep half ----
        int p = blockIdx.x - 512;
        int s = p >> 7;
        int idx = (p & 127)*128 + t;
        if (s < 4){
            int K = a.K[s], O = a.O[s];
            if (idx >= K*O) return;
            int k = idx / O, j = idx - k*O;
            wpf[a.off[s] + idx] = ldin(a.w[s], (size_t)j*K + k, f32);
        } else {
            if (idx >= 16384) return;
            int n = idx >> 7, k = idx & 127;
            float v = ldin(a.w[s], (size_t)n*128 + k, f32);
            ushort_t h = f2bf(v);
            ushort_t l = f2bf(v - bf2f(h));
            int di = (s - 4)*16384 + ((k >> 3)*128 + n)*8 + (k & 7);
            whi[di] = h; wlo[di] = l;
        }
        return;
    }

    // ---- bnlin12 half ----
    __shared__ __align__(16) float wt1[32*64];      // 8 KB
    __shared__ __align__(16) float wt2[64*128];     // 32 KB
    __shared__ __align__(16) float xst[2][32*36];   // 9.2 KB
    __shared__ __align__(16) float cst[2][64*36];   // 18.4 KB
    int w = t >> 6, lane = t & 63;
    int n = blockIdx.x*2 + w;

    // inline transpose of raw e1 [64][32] and e2 [128][64] into LDS
    for (int i = t; i < 2048; i += 128)
        wt1[(i & 31)*64 + (i >> 5)] = ldin(e1w, i, f32);
    for (int i = t; i < 8192; i += 128)
        wt2[(i & 63)*128 + (i >> 6)] = ldin(e2w, i, f32);
    for (int i = lane; i < 32*4; i += 64){
        int b = i >> 2, g = i & 3;
        float f[8];
        if (f32){
            const float* src = (const float*)xin + ((size_t)b*NN + n)*32 + g*8;
            float4 v0 = ((const float4*)src)[0];
            float4 v1 = ((const float4*)src)[1];
            f[0]=v0.x; f[1]=v0.y; f[2]=v0.z; f[3]=v0.w;
            f[4]=v1.x; f[5]=v1.y; f[6]=v1.z; f[7]=v1.w;
        } else {
            uint4 v = *(const uint4*)((const ushort_t*)xin + ((size_t)b*NN + n)*32 + (size_t)g*8);
            unpack8(v, f);
        }
        #pragma unroll
        for (int j=0;j<8;j++) xst[w][(g*8+j)*36 + b] = f[j];
    }
    __syncthreads();

    // ---- layer 1: K=32, O=64.  lane -> b0=(lane%8)*4, j0=(lane/8)*8 ----
    {
        int b0 = (lane & 7)*4, j0 = (lane >> 3)*8;
        float acc[4][8];
        #pragma unroll
        for (int i=0;i<4;i++)
            #pragma unroll
            for (int j=0;j<8;j++) acc[i][j] = 0.f;
        for (int k = 0; k < 32; k++){
            float xv[4], wv[8];
            *(float4*)&xv[0] = *(const float4*)&xst[w][k*36 + b0];
            *(float4*)&wv[0] = *(const float4*)&wt1[k*64 + j0];
            *(float4*)&wv[4] = *(const float4*)&wt1[k*64 + j0 + 4];
            #pragma unroll
            for (int i=0;i<4;i++)
                #pragma unroll
                for (int j=0;j<8;j++) acc[i][j] = fmaf(xv[i], wv[j], acc[i][j]);
        }
        float bj[8];
        #pragma unroll
        for (int j=0;j<8;j++) bj[j] = ldin(b1v, j0+j, f32);
        float s1 = 0.f, s2 = 0.f;
        #pragma unroll
        for (int i=0;i<4;i++)
            #pragma unroll
            for (int j=0;j<8;j++){
                float a2 = acc[i][j] + bj[j];
                acc[i][j] = a2; s1 += a2; s2 = fmaf(a2, a2, s2);
            }
        #pragma unroll
        for (int off = 32; off > 0; off >>= 1){
            s1 += __shfl_down(s1, off);
            s2 += __shfl_down(s2, off);
        }
        s1 = __shfl(s1, 0); s2 = __shfl(s2, 0);
        float m  = s1 / 2048.f;
        float vv = s2 / 2048.f - m*m;
        float rs = rsqrtf(vv + 1e-5f);
        float gv = ldin(g1, n, f32), bv = ldin(bb1, n, f32);
        #pragma unroll
        for (int i=0;i<4;i++)
            #pragma unroll
            for (int j=0;j<8;j++)
                cst[w][(j0+j)*36 + b0+i] =
                    fmaxf(fmaf(gv*(acc[i][j]-m), rs, bv), 0.f);
    }
    __syncthreads();

    // ---- layer 2: K=64, O=128.  lane -> b0=(lane%4)*8, j0=(lane/4)*8 ----
    {
        int b0 = (lane & 3)*8, j0 = (lane >> 2)*8;
        float acc[8][8];
        #pragma unroll
        for (int i=0;i<8;i++)
            #pragma unroll
            for (int j=0;j<8;j++) acc[i][j] = 0.f;
        for (int k = 0; k < 64; k++){
            float xv[8], wv[8];
            *(float4*)&xv[0] = *(const float4*)&cst[w][k*36 + b0];
            *(float4*)&xv[4] = *(const float4*)&cst[w][k*36 + b0 + 4];
            *(float4*)&wv[0] = *(const float4*)&wt2[k*128 + j0];
            *(float4*)&wv[4] = *(const float4*)&wt2[k*128 + j0 + 4];
            #pragma unroll
            for (int i=0;i<8;i++)
                #pragma unroll
                for (int j=0;j<8;j++) acc[i][j] = fmaf(xv[i], wv[j], acc[i][j]);
        }
        float bj[8];
        #pragma unroll
        for (int j=0;j<8;j++) bj[j] = ldin(b2v, j0+j, f32);
        float s1 = 0.f, s2 = 0.f;
        #pragma unroll
        for (int i=0;i<8;i++)
            #pragma unroll
            for (int j=0;j<8;j++){
                float a2 = acc[i][j] + bj[j];
                acc[i][j] = a2; s1 += a2; s2 = fmaf(a2, a2, s2);
            }
        #pragma unroll
        for (int off = 32; off > 0; off >>= 1){
            s1 += __shfl_down(s1, off);
            s2 += __shfl_down(s2, off);
        }
        s1 = __shfl(s1, 0); s2 = __shfl(s2, 0);
        float m  = s1 / 4096.f;
        float vv = s2 / 4096.f - m*m;
        float rs = rsqrtf(vv + 1e-5f);
        float gv = ldin(g2, n, f32), bv = ldin(bb2, n, f32);
        #pragma unroll
        for (int i=0;i<8;i++){
            union { uint4 u; ushort_t s[8]; } pk;
            #pragma unroll
            for (int j=0;j<8;j++)
                pk.s[j] = f2bf(fmaxf(fmaf(gv*(acc[i][j]-m), rs, bv), 0.f));
            *(uint4*)(out + ((size_t)(b0+i)*NN + n)*128 + j0) = pk.u;
        }
    }
}

// ---------------- merged: decoder lin+BN+ReLU (128->64) + dec tail ---------
// block = 128 thr; wave w owns channel n = bx*2 + w.  After BN, activations
// are bf16-rounded into LDS (replicating the old Cdec path bit-exactly) and
// the 64->32 relu + 32->{28,4} output layers run in-block.
__global__ __launch_bounds__(128) void k_dectail(
    const ushort_t* __restrict__ xin,          // A [32768][128] bf16
    const float* __restrict__ W1t,             // [128][64] (d1 transposed)
    const void* __restrict__ d1b, const void* __restrict__ bng,
    const void* __restrict__ bnb,
    const float* __restrict__ W2t,             // [64][32]
    const void* __restrict__ b2,
    const float* __restrict__ Wct, const void* __restrict__ bcb,
    const float* __restrict__ Wgt, const void* __restrict__ bgb,
    void* __restrict__ out, const void* __restrict__ detin)
{
    __shared__ __align__(16) float smem[8192 + 9216];   // 69.6 KB
    float* wt  = smem;            // [128][64] d1 weights; later dec weights
    float* xst = smem + 8192;     // [2][128*36] inputs; later cst/hs
    int f32 = detect_dev(detin);
    int t = threadIdx.x;
    int w = t >> 6, lane = t & 63;
    int n = blockIdx.x*2 + w;

    for (int i = t; i < 8192/4; i += 128)
        ((float4*)wt)[i] = ((const float4*)W1t)[i];
    float* xw = xst + w*4608;
    for (int i = lane; i < 32*16; i += 64){
        int b = i >> 4, g = i & 15;
        float f[8];
        uint4 v = *(const uint4*)(xin + ((size_t)b*NN + n)*128 + (size_t)g*8);
        unpack8(v, f);
        #pragma unroll
        for (int j=0;j<8;j++) xw[(g*8+j)*36 + b] = f[j];
    }
    __syncthreads();

    // ---- d1 GEMM (K=128, O=64) + BN stats, lane -> b0=(lane%8)*4, j0=(lane/8)*8
    int b0 = (lane & 7)*4, j0 = (lane >> 3)*8;
    float acc[4][8];
    #pragma unroll
    for (int i=0;i<4;i++)
        #pragma unroll
        for (int j=0;j<8;j++) acc[i][j] = 0.f;
    for (int k = 0; k < 128; k++){
        float xv[4], wv[8];
        *(float4*)&xv[0] = *(const float4*)&xw[k*36 + b0];
        *(float4*)&wv[0] = *(const float4*)&wt[k*64 + j0];
        *(float4*)&wv[4] = *(const float4*)&wt[k*64 + j0 + 4];
        #pragma unroll
        for (int i=0;i<4;i++)
            #pragma unroll
            for (int j=0;j<8;j++) acc[i][j] = fmaf(xv[i], wv[j], acc[i][j]);
    }
    float bj[8];
    #pragma unroll
    for (int j=0;j<8;j++) bj[j] = ldin(d1b, j0+j, f32);
    float s1 = 0.f, s2 = 0.f;
    #pragma unroll
    for (int i=0;i<4;i++)
        #pragma unroll
        for (int j=0;j<8;j++){
            float a2 = acc[i][j] + bj[j];
            acc[i][j] = a2; s1 += a2; s2 = fmaf(a2, a2, s2);
        }
    #pragma unroll
    for (int off = 32; off > 0; off >>= 1){
        s1 += __shfl_down(s1, off);
        s2 += __shfl_down(s2, off);
    }
    s1 = __shfl(s1, 0); s2 = __shfl(s2, 0);
    float m  = s1 / 2048.f;
    float vv = s2 / 2048.f - m*m;
    float rs = rsqrtf(vv + 1e-5f);
    float gv = ldin(bng, n, f32), bv = ldin(bnb, n, f32);
    __syncthreads();                 // wt / xst reads complete

    // ---- overlay: dec weights into wt region, cst/hs into xst region ----
    float* w2s  = wt;                // 2048 f
    float* wcs  = wt + 2048;         // 896 f
    float* wgs  = wt + 2944;         // 128 f
    float* cstw = xst + w*2080;      // [32][65] per wave
    float* hsw  = xst + 4160 + w*1056;   // [32][33] per wave
    for (int i = t; i < 512; i += 128) ((float4*)w2s)[i] = ((const float4*)W2t)[i];
    for (int i = t; i < 224; i += 128) ((float4*)wcs)[i] = ((const float4*)Wct)[i];
    if (t < 32) ((float4*)wgs)[t] = ((const float4*)Wgt)[t];
    #pragma unroll
    for (int i=0;i<4;i++)
        #pragma unroll
        for (int j=0;j<8;j++){
            float val = fmaxf(fmaf(gv*(acc[i][j]-m), rs, bv), 0.f);
            cstw[(b0+i)*65 + (j0+j)] = bf2f(f2bf(val));   // Cdec-exact rounding
        }
    __syncthreads();

    // ---- dec tail: lane -> (b = lane&31, jg = lane>>5) ----
    int b = lane & 31, jg = lane >> 5;
    float h[16];
    #pragma unroll
    for (int jj=0;jj<16;jj++) h[jj] = ldin(b2, jg*16+jj, f32);
    for (int k = 0; k < 64; k++){
        float xv = cstw[b*65 + k];
        #pragma unroll
        for (int jj=0;jj<16;jj++)
            h[jj] = fmaf(xv, w2s[k*32 + jg*16 + jj], h[jj]);
    }
    #pragma unroll
    for (int jj=0;jj<16;jj++) hsw[b*33 + jg*16 + jj] = fmaxf(h[jj], 0.f);
    __syncthreads();
    #pragma unroll
    for (int jj=0;jj<16;jj++){
        int j2 = jg*16 + jj;
        float o;
        if (j2 < 28){
            o = ldin(bcb, j2, f32);
            #pragma unroll
            for (int k=0;k<32;k++) o = fmaf(hsw[b*33 + k], wcs[k*28 + j2], o);
        } else {
            int gg = j2 - 28;
            o = ldin(bgb, gg, f32);
            #pragma unroll
            for (int k=0;k<32;k++) o = fmaf(hsw[b*33 + k], wgs[k*4 + gg], o);
        }
        size_t oi = ((size_t)b*NN + n)*32 + j2;
        if (f32) ((float*)out)[oi] = o;
        else     ((ushort_t*)out)[oi] = f2bf(o);
    }
}

// ---------------- shared tails for the fused MFMA kernels (64-row) ---------
__device__ __forceinline__ void tail_stage_x(ushort_t* xs, ushort_t* xt,
                                             const float o[2][16],
                                             int w, int col, int quad){
    #pragma unroll
    for (int nt=0;nt<2;nt++){
        int n = w*32 + nt*16 + col;
        #pragma unroll
        for (int m=0;m<4;m++){
            union { uint2 u2; ushort_t s[4]; } pk;
            #pragma unroll
            for (int reg=0;reg<4;reg++){
                int r = m*16 + quad*4 + reg;
                ushort_t hv = f2bf(o[nt][m*4+reg]);
                xs[((n>>3)*64 + r)*8 + (n&7)] = hv;
                pk.s[reg] = hv;
            }
            *(uint2*)&xt[n*XSTRIDE + m*16 + quad*4] = pk.u2;
        }
    }
}

__device__ __forceinline__ void tail_write_A(const ushort_t* xs, ushort_t* A,
                                             size_t row0, int t){
    uint4* dst = (uint4*)(A + row0*128);
    #pragma unroll
    for (int c = 0; c < 4; c++){
        int i = t + c*256;
        int r = i >> 4, kg = i & 15;
        dst[i] = *(const uint4*)&xs[(kg*64 + r)*8];
    }
}

// 128x128 MFMA with hi/lo-split B operand (B layout: [(kg*128 + n)*8]).
__device__ __forceinline__ void mfma_hilo(const ushort_t* xs,
    const ushort_t* Bh, const ushort_t* Bl, v4f acc[4][2],
    int w, int col, int quad)
{
    #pragma unroll
    for (int m=0;m<4;m++)
        #pragma unroll
        for (int nt=0;nt<2;nt++) acc[m][nt] = (v4f){0.f,0.f,0.f,0.f};
    #pragma unroll
    for (int kt = 0; kt < 4; kt++){
        int kg = kt*4 + quad;
        v8s a[4], bh[2], bl[2];
        #pragma unroll
        for (int nt=0;nt<2;nt++){
            int n = w*32 + nt*16 + col;
            bh[nt] = *(const v8s*)&Bh[(kg*128 + n)*8];
            bl[nt] = *(const v8s*)&Bl[(kg*128 + n)*8];
        }
        #pragma unroll
        for (int m=0;m<4;m++)
            a[m] = *(const v8s*)&xs[(kg*64 + m*16 + col)*8];
        #pragma unroll
        for (int m=0;m<4;m++)
            #pragma unroll
            for (int nt=0;nt<2;nt++){
                acc[m][nt] = MFMA_BF16(a[m], bh[nt], acc[m][nt], 0, 0, 0);
                acc[m][nt] = MFMA_BF16(a[m], bl[nt], acc[m][nt], 0, 0, 0);
            }
    }
}

// next linear: U = relu(x'·W^T + b) -> xs [n][XSTRIDE]; then the block's
// 64-row T-partial  Tp[s][b][c][n] (bf16) = sum_r u[r][n] * x'[r][c].
__device__ __forceinline__ void tail_lin_relu_T(ushort_t* xs, ushort_t* xt,
    const ushort_t* Whi, const ushort_t* Wlo, const void* bias,
    ushort_t* Tp, size_t row0, int t, int w, int col, int quad, int f32)
{
    v4f acc[4][2];
    mfma_hilo(xs, Whi, Wlo, acc, w, col, quad);
    float u[2][16];
    #pragma unroll
    for (int nt=0;nt<2;nt++){
        int n = w*32 + nt*16 + col;
        float bn = ldin(bias, n, f32);
        #pragma unroll
        for (int m=0;m<4;m++)
            #pragma unroll
            for (int reg=0;reg<4;reg++)
                u[nt][m*4+reg] = fmaxf(acc[m][nt][reg] + bn, 0.f);
    }
    __syncthreads();           // xs A-frag reads done
    #pragma unroll
    for (int nt=0;nt<2;nt++){
        int n = w*32 + nt*16 + col;
        #pragma unroll
        for (int m=0;m<4;m++){
            union { uint2 u2; ushort_t s[4]; } pk;
            #pragma unroll
            for (int reg=0;reg<4;reg++)
                pk.s[reg] = f2bf(u[nt][m*4+reg]);
            *(uint2*)&xs[n*XSTRIDE + m*16 + quad*4] = pk.u2;  // u in [n][72r]
        }
    }
    __syncthreads();
    v4f tacc[4][4];
    #pragma unroll
    for (int m=0;m<4;m++)
        #pragma unroll
        for (int q=0;q<4;q++) tacc[m][q] = (v4f){0.f,0.f,0.f,0.f};
    int wn = (w & 1)*64, wc = (w >> 1)*64;
    #pragma unroll
    for (int kt = 0; kt < 2; kt++){
        int kg = kt*4 + quad;
        v8s a[4], bb[4];
        #pragma unroll
        for (int m=0;m<4;m++)
            a[m] = *(const v8s*)&xs[(wn + m*16 + col)*XSTRIDE + kg*8];
        #pragma unroll
        for (int q=0;q<4;q++)
            bb[q] = *(const v8s*)&xt[(wc + q*16 + col)*XSTRIDE + kg*8];
        #pragma unroll
        for (int m=0;m<4;m++)
            #pragma unroll
            for (int q=0;q<4;q++)
                tacc[m][q] = MFMA_BF16(a[m], bb[q], tacc[m][q], 0, 0, 0);
    }
    int s16 = (int)((row0 >> 6) & 15);
    int b   = (int)(row0 >> 10);
    ushort_t* dst = Tp + ((size_t)(s16*NB + b) << 14);   // [c][n] bf16
    #pragma unroll
    for (int m=0;m<4;m++)
        #pragma unroll
        for (int q=0;q<4;q++){
            int c = wc + q*16 + col;
            union { uint2 u2; ushort_t s[4]; } pk;
            #pragma unroll
            for (int reg=0;reg<4;reg++)
                pk.s[reg] = f2bf(tacc[m][q][reg]);       // n-consecutive
            *(uint2*)&dst[c*128 + wn + m*16 + quad*4] = pk.u2;
        }
}

// ---------------- fused: enc3 sigmoid + relation-1 U + T-partial -----------
__global__ __launch_bounds__(256) void k_linfuse0(
    const ushort_t* __restrict__ xin,                 // E2, row-major
    const ushort_t* __restrict__ W3h, const ushort_t* __restrict__ W3l,
    const void* __restrict__ b3,
    const ushort_t* __restrict__ W1h, const ushort_t* __restrict__ W1l,
    const void* __restrict__ b1,
    ushort_t* __restrict__ A, ushort_t* __restrict__ Tp,
    const void* __restrict__ detin)
{
    __shared__ __align__(16) ushort_t xs[128*XSTRIDE];
    __shared__ __align__(16) ushort_t xt[128*XSTRIDE];
    int f32 = detect_dev(detin);
    int t = threadIdx.x;
    size_t row0 = (size_t)blockIdx.x * 64;
    {
        const uint4* src = (const uint4*)(xin + row0*128);
        #pragma unroll
        for (int c = 0; c < 4; c++){
            int i = t + c*256;
            int r = i >> 4, kg = i & 15;
            *(uint4*)&xs[(kg*64 + r)*8] = src[i];
        }
    }
    __syncthreads();
    int w = t >> 6, lane = t & 63;
    int col = lane & 15, quad = lane >> 4;
    v4f acc[4][2];
    mfma_hilo(xs, W3h, W3l, acc, w, col, quad);
    float o[2][16];
    #pragma unroll
    for (int nt=0;nt<2;nt++){
        int n = w*32 + nt*16 + col;
        float bn = ldin(b3, n, f32);
        #pragma unroll
        for (int m=0;m<4;m++)
            #pragma unroll
            for (int reg=0;reg<4;reg++){
                float v = acc[m][nt][reg] + bn;
                o[nt][m*4+reg] = 1.f/(1.f+expf(-v));
            }
    }
    __syncthreads();
    tail_stage_x(xs, xt, o, w, col, quad);
    __syncthreads();
    tail_write_A(xs, A, row0, t);
    tail_lin_relu_T(xs, xt, W1h, W1l, b1, Tp, row0, t, w, col, quad, f32);
}

// ---------------- reduce 16 bf16 partials -> Tt hi/lo (MFMA-B layout) ------
__global__ __launch_bounds__(256) void k_tredb(const ushort_t* __restrict__ Tp,
                                               ushort_t* __restrict__ Thi, ushort_t* __restrict__ Tlo){
    int tau = blockIdx.x*256 + threadIdx.x;     // 65536 total
    int b = tau >> 11;
    int j2 = tau & 2047;
    int cg = j2 >> 7, n = j2 & 127;
    float sum[8] = {0,0,0,0,0,0,0,0};
    #pragma unroll
    for (int s = 0; s < 16; s++){
        const ushort_t* src = Tp + ((size_t)(s*NB + b) << 14) + cg*8*128 + n;
        #pragma unroll
        for (int cc = 0; cc < 8; cc++)
            sum[cc] += bf2f(src[cc*128]);
    }
    union { uint4 u; ushort_t s[8]; } ph, pl;
    #pragma unroll
    for (int cc = 0; cc < 8; cc++){
        ushort_t h = f2bf(sum[cc]);
        ph.s[cc] = h;
        pl.s[cc] = f2bf(sum[cc] - bf2f(h));
    }
    size_t di = ((size_t)b << 14) + ((size_t)cg*128 + n)*8;
    *(uint4*)&Thi[di] = ph.u;
    *(uint4*)&Tlo[di] = pl.u;
}

// ---------------- fused: relout_r (+ lin_{r+1} + T-partial unless LAST) ----
template<int LAST>
__global__ __launch_bounds__(256) void k_relfuse(
    ushort_t* __restrict__ x,
    const ushort_t* __restrict__ Thi, const ushort_t* __restrict__ Tlo,
    const void* __restrict__ psi, const void* __restrict__ phi, const void* __restrict__ wr,
    const ushort_t* __restrict__ Wrh, const ushort_t* __restrict__ Wrl,
    const void* __restrict__ rbias,
    const ushort_t* __restrict__ Wnh, const ushort_t* __restrict__ Wnl,
    const void* __restrict__ bnext, ushort_t* __restrict__ Tp,
    const void* __restrict__ detin)
{
    __shared__ __align__(16) ushort_t xs[128*XSTRIDE];
    __shared__ __align__(16) ushort_t xt[128*XSTRIDE];
    __shared__ __align__(16) float sdvec[64];
    int f32 = detect_dev(detin);
    int t = threadIdx.x;
    size_t row0 = (size_t)blockIdx.x * 64;
    int b = (int)(row0 >> 10);
    {
        const uint4* src = (const uint4*)(x + row0*128);
        #pragma unroll
        for (int c = 0; c < 4; c++){
            int i = t + c*256;
            int r = i >> 4, kg = i & 15;
            *(uint4*)&xs[(kg*64 + r)*8] = src[i];
        }
    }
    __syncthreads();
    int w = t >> 6, lane = t & 63;
    int col = lane & 15, quad = lane >> 4;

    // ---- head: recompute sdvec = |x'_row|^2 and u = relu(W_r x' + b_r) ----
    if (t < 64){
        float s = 0.f;
        #pragma unroll 8
        for (int k=0;k<128;k++){
            float v = bf2f(xs[((k>>3)*64 + t)*8 + (k&7)]);
            s = fmaf(v, v, s);
        }
        sdvec[t] = s;
    }
    {
        v4f uacc[4][2];
        mfma_hilo(xs, Wrh, Wrl, uacc, w, col, quad);
        #pragma unroll
        for (int nt=0;nt<2;nt++){
            int n = w*32 + nt*16 + col;
            float bn = ldin(rbias, n, f32);
            #pragma unroll
            for (int m=0;m<4;m++){
                union { uint2 u2; ushort_t s[4]; } pk;
                #pragma unroll
                for (int reg=0;reg<4;reg++)
                    pk.s[reg] = f2bf(fmaxf(uacc[m][nt][reg] + bn, 0.f));
                *(uint2*)&xt[n*XSTRIDE + m*16 + quad*4] = pk.u2;  // u [n][72r]
            }
        }
    }
    __syncthreads();           // u + sdvec ready

    float alpha = ldin(wr,0,f32) * ldin(psi,0,f32) * ldin(phi,0,f32) * (1.f/1024.f);
    const ushort_t* sh = Thi + ((size_t)b << 14);
    const ushort_t* sl = Tlo + ((size_t)b << 14);
    v4f acc[4][2];
    mfma_hilo(xs, sh, sl, acc, w, col, quad);
    float o[2][16];
    #pragma unroll
    for (int m=0;m<4;m++){
        float4 d4 = *(const float4*)&sdvec[m*16 + quad*4];
        const float* dr = (const float*)&d4;
        #pragma unroll
        for (int nt=0;nt<2;nt++){
            int n = w*32 + nt*16 + col;
            #pragma unroll
            for (int reg=0;reg<4;reg++){
                int r = m*16 + quad*4 + reg;
                float ufv = bf2f(xt[n*XSTRIDE + r]);     // u (recomputed)
                float xv = bf2f(xs[((n>>3)*64 + r)*8 + (n&7)]);
                o[nt][m*4+reg] = fmaf(alpha, acc[m][nt][reg] - dr[reg]*ufv, xv);
            }
        }
    }
    __syncthreads();           // all xs / xt / sdvec reads done
    tail_stage_x(xs, xt, o, w, col, quad);
    __syncthreads();
    tail_write_A(xs, x, row0, t);
    if (!LAST)
        tail_lin_relu_T(xs, xt, Wnh, Wnl, bnext, Tp,
                        row0, t, w, col, quad, f32);
}

// ---------------------------------------------------------------------------
enum { O_E1=0, O_E2=2048, O_D1=10240, O_D2=18432, O_BC=20480, O_BG=21376 };

extern "C" void kernel_launch(void* const* d_in, const int* in_sizes, int n_in,
                              void* d_out, int out_size, void* d_ws, size_t ws_size,
                              hipStream_t stream)
{
    (void)in_sizes; (void)n_in; (void)out_size; (void)ws_size;
    const void* input = d_in[0];
    const void* e1_W = d_in[1];  const void* e1_b = d_in[2];
    const void* bn1_g = d_in[3]; const void* bn1_b = d_in[4];
    const void* e2_W = d_in[5];  const void* e2_b = d_in[6];
    const void* bn2_g = d_in[7]; const void* bn2_b = d_in[8];
    const void* e3_W = d_in[9];  const void* e3_b = d_in[10];
    const void *rW[4], *rb[4], *rpsi[4], *rphi[4], *rwr[4];
    for (int r = 0; r < 4; r++){
        rW[r]   = d_in[11 + r*5 + 0];
        rb[r]   = d_in[11 + r*5 + 1];
        rpsi[r] = d_in[11 + r*5 + 2];
        rphi[r] = d_in[11 + r*5 + 3];
        rwr[r]  = d_in[11 + r*5 + 4];
    }
    const void* d1_W = d_in[31]; const void* d1_b = d_in[32];
    const void* dbn_g = d_in[33];const void* dbn_b = d_in[34];
    const void* d2_W = d_in[35]; const void* d2_b = d_in[36];
    const void* bc_W = d_in[37]; const void* bc_b = d_in[38];
    const void* bg_W = d_in[39]; const void* bg_b = d_in[40];

    // ---- workspace layout, float offsets (all 16B-aligned) ----
    float*    ws_f = (float*)d_ws;
    float*    wpf  = ws_f;                          // 21504 f
    ushort_t* whi  = (ushort_t*)(ws_f + 54272);     // 5*16384 us
    ushort_t* wlo  = (ushort_t*)(ws_f + 95232);     // 5*16384 us
    ushort_t* Thi  = (ushort_t*)(ws_f + 136192);    // 524288 us
    ushort_t* Tlo  = (ushort_t*)(ws_f + 398336);    // 524288 us
    ushort_t* Tp   = (ushort_t*)(ws_f + 660480);    // 16*32*16384 us (bf16)
    ushort_t* A    = (ushort_t*)(ws_f + 4854784);   // [32768][128] bf16
    ushort_t* E2   = (ushort_t*)(ws_f + 9049088);   // [32768][128] bf16

    PrepArgs pa;
    const void* srcs[9] = {d1_W, d2_W, bc_W, bg_W,
                           e3_W, rW[0], rW[1], rW[2], rW[3]};
    const int  Ks[9]   = {128,64,32,32, 128,128,128,128,128};
    const int  Os[9]   = {64,32,28,4,   128,128,128,128,128};
    const int  offs[9] = {O_D1,O_D2,O_BC,O_BG, 0,0,0,0,0};
    for (int i=0;i<9;i++){ pa.w[i]=srcs[i]; pa.K[i]=Ks[i]; pa.O[i]=Os[i]; pa.off[i]=offs[i]; }

    k_enc0<<<512 + 9*128, 128, 0, stream>>>(pa, wpf, whi, wlo,
                                            input, e1_W, e1_b, bn1_g, bn1_b,
                                            e2_W, e2_b, bn2_g, bn2_b,
                                            E2, input);
    k_linfuse0<<<512, 256, 0, stream>>>(E2, whi, wlo, e3_b,
                                        whi + 16384, wlo + 16384, rb[0],
                                        A, Tp, input);

    for (int r = 0; r < 4; r++){
        k_tredb<<<256, 256, 0, stream>>>(Tp, Thi, Tlo);
        if (r < 3)
            k_relfuse<0><<<512, 256, 0, stream>>>(A, Thi, Tlo,
                rpsi[r], rphi[r], rwr[r],
                whi + (size_t)(1+r)*16384, wlo + (size_t)(1+r)*16384, rb[r],
                whi + (size_t)(2+r)*16384, wlo + (size_t)(2+r)*16384, rb[r+1],
                Tp, input);
        else
            k_relfuse<1><<<512, 256, 0, stream>>>(A, Thi, Tlo,
                rpsi[r], rphi[r], rwr[r],
                whi + (size_t)4*16384, wlo + (size_t)4*16384, rb[3],
                whi, wlo, rb[0],
                Tp, input);
    }

    k_dectail<<<512, 128, 0, stream>>>(A, wpf+O_D1, d1_b, dbn_g, dbn_b,
                                       wpf+O_D2, d2_b, wpf+O_BC, bc_b,
                                       wpf+O_BG, bg_b, d_out, input);
}

// Round 6
// 292.433 us; speedup vs baseline: 1.0640x; 1.0640x over previous
//
#include <hip/hip_runtime.h>
#include <hip/hip_bf16.h>

// ---------------------------------------------------------------------------
// Generator_58737972740271.  R19 = R18 with k_enc0 repaired.
// R18 post-mortem: k_enc0 = 46us, 5.17M LDS bank conflicts (stride-64/128
// transpose writes = 32-way conflicts) + 1152 prep rider blocks each paying
// the 69KB LDS allocation (2 blk/CU => serialized scheduling waves).
// R19 fixes, numerics bit-identical:
//  (1) prep striped INTO the 512 encoder blocks (grid-stride, ~2 elems/thr,
//      stores overlap encoder compute) -- grid back to 512, no rider blocks.
//  (2) j-major transpose: thread (kq,j) reads 4-wide from raw weight row j,
//      writes wt[(4kq+c)*O + j] -- consecutive lanes -> consecutive LDS
//      addresses -> conflict-free.  Same float values (bf16->f32 exact).
// k_dectail (bnlin128x64 + dec2 merge, Cdec-exact bf16 rounding) kept.
// ---------------------------------------------------------------------------

typedef __hip_bfloat16 bf16;
typedef unsigned short ushort_t;
typedef float v4f __attribute__((ext_vector_type(4)));
typedef short v8s __attribute__((ext_vector_type(8)));
#define MFMA_BF16 __builtin_amdgcn_mfma_f32_16x16x32_bf16

#define NB 32
#define NN 1024
#define XSTRIDE 72   // padded [n][r] stride (16B-aligned, breaks bank conflicts)

__device__ __forceinline__ float ldin(const void* p, size_t i, int f32){
    return f32 ? ((const float*)p)[i] : __bfloat162float(((const bf16*)p)[i]);
}
__device__ __forceinline__ float bf2f(ushort_t u){
    return __uint_as_float((unsigned)u << 16);
}
__device__ __forceinline__ ushort_t f2bf(float v){
    bf16 h = __float2bfloat16(v);
    ushort_t s; __builtin_memcpy(&s, &h, 2);
    return s;
}
__device__ __forceinline__ void unpack8(uint4 v, float* f){
    f[0] = __uint_as_float(v.x << 16);
    f[1] = __uint_as_float(v.x & 0xffff0000u);
    f[2] = __uint_as_float(v.y << 16);
    f[3] = __uint_as_float(v.y & 0xffff0000u);
    f[4] = __uint_as_float(v.z << 16);
    f[5] = __uint_as_float(v.z & 0xffff0000u);
    f[6] = __uint_as_float(v.w << 16);
    f[7] = __uint_as_float(v.w & 0xffff0000u);
}
__device__ __forceinline__ void unpack4(uint2 v, float* f){
    f[0] = __uint_as_float(v.x << 16);
    f[1] = __uint_as_float(v.x & 0xffff0000u);
    f[2] = __uint_as_float(v.y << 16);
    f[3] = __uint_as_float(v.y & 0xffff0000u);
}

__device__ __forceinline__ int detect_dev(const void* inp){
    __shared__ int sflag;
    int t = threadIdx.x;
    if (t < 64){
        unsigned v = ((const unsigned*)inp)[t];
        unsigned long long m = __ballot((v & 0x80008000u) != 0u);
        if (t == 0) sflag = (__popcll(m) > 4) ? 1 : 0;
    }
    __syncthreads();
    return sflag;
}

// ---------------- merged: weight prep (striped) + encoder lin/BN/ReLU x2 ---
struct PrepArgs {
    const void* w[9];
    int K[9], O[9], off[9];
};

__global__ __launch_bounds__(128) void k_enc0(PrepArgs a, float* __restrict__ wpf,
    ushort_t* __restrict__ whi, ushort_t* __restrict__ wlo,
    const void* __restrict__ xin,
    const void* __restrict__ e1w, const void* __restrict__ b1v,
    const void* __restrict__ g1, const void* __restrict__ bb1,
    const void* __restrict__ e2w, const void* __restrict__ b2v,
    const void* __restrict__ g2, const void* __restrict__ bb2,
    ushort_t* __restrict__ out, const void* __restrict__ detin)
{
    int f32 = detect_dev(detin);
    int t = threadIdx.x;

    // ---- prep stripe: each block converts its share of the 9 weight sets --
    #pragma unroll 1
    for (int s = 0; s < 9; s++){
        int K = a.K[s], O = a.O[s];
        int tot = (s < 4) ? K*O : 16384;
        for (int idx = blockIdx.x*128 + t; idx < tot; idx += 512*128){
            if (s < 4){
                int k = idx / O, j = idx - k*O;
                wpf[a.off[s] + idx] = ldin(a.w[s], (size_t)j*K + k, f32);
            } else {
                int n = idx >> 7, k = idx & 127;
                float v = ldin(a.w[s], (size_t)n*128 + k, f32);
                ushort_t h = f2bf(v);
                ushort_t l = f2bf(v - bf2f(h));
                int di = (s - 4)*16384 + ((k >> 3)*128 + n)*8 + (k & 7);
                whi[di] = h; wlo[di] = l;
            }
        }
    }

    // ---- encoder ----
    __shared__ __align__(16) float wt1[32*64];      // 8 KB
    __shared__ __align__(16) float wt2[64*128];     // 32 KB
    __shared__ __align__(16) float xst[2][32*36];   // 9.2 KB
    __shared__ __align__(16) float cst[2][64*36];   // 18.4 KB
    int w = t >> 6, lane = t & 63;
    int n = blockIdx.x*2 + w;

    // j-major transpose of e1 [64][32] -> wt1 [32][64] (conflict-free writes)
    for (int i = t; i < 512; i += 128){
        int kq = i >> 6, j = i & 63;
        float f[4];
        if (f32){
            float4 v = *(const float4*)((const float*)e1w + (size_t)j*32 + kq*4);
            f[0]=v.x; f[1]=v.y; f[2]=v.z; f[3]=v.w;
        } else {
            uint2 v = *(const uint2*)((const ushort_t*)e1w + (size_t)j*32 + kq*4);
            unpack4(v, f);
        }
        #pragma unroll
        for (int c=0;c<4;c++) wt1[(kq*4+c)*64 + j] = f[c];
    }
    // j-major transpose of e2 [128][64] -> wt2 [64][128]
    for (int i = t; i < 2048; i += 128){
        int kq = i >> 7, j = i & 127;
        float f[4];
        if (f32){
            float4 v = *(const float4*)((const float*)e2w + (size_t)j*64 + kq*4);
            f[0]=v.x; f[1]=v.y; f[2]=v.z; f[3]=v.w;
        } else {
            uint2 v = *(const uint2*)((const ushort_t*)e2w + (size_t)j*64 + kq*4);
            unpack4(v, f);
        }
        #pragma unroll
        for (int c=0;c<4;c++) wt2[(kq*4+c)*128 + j] = f[c];
    }
    for (int i = lane; i < 32*4; i += 64){
        int b = i >> 2, g = i & 3;
        float f[8];
        if (f32){
            const float* src = (const float*)xin + ((size_t)b*NN + n)*32 + g*8;
            float4 v0 = ((const float4*)src)[0];
            float4 v1 = ((const float4*)src)[1];
            f[0]=v0.x; f[1]=v0.y; f[2]=v0.z; f[3]=v0.w;
            f[4]=v1.x; f[5]=v1.y; f[6]=v1.z; f[7]=v1.w;
        } else {
            uint4 v = *(const uint4*)((const ushort_t*)xin + ((size_t)b*NN + n)*32 + (size_t)g*8);
            unpack8(v, f);
        }
        #pragma unroll
        for (int j=0;j<8;j++) xst[w][(g*8+j)*36 + b] = f[j];
    }
    __syncthreads();

    // ---- layer 1: K=32, O=64.  lane -> b0=(lane%8)*4, j0=(lane/8)*8 ----
    {
        int b0 = (lane & 7)*4, j0 = (lane >> 3)*8;
        float acc[4][8];
        #pragma unroll
        for (int i=0;i<4;i++)
            #pragma unroll
            for (int j=0;j<8;j++) acc[i][j] = 0.f;
        for (int k = 0; k < 32; k++){
            float xv[4], wv[8];
            *(float4*)&xv[0] = *(const float4*)&xst[w][k*36 + b0];
            *(float4*)&wv[0] = *(const float4*)&wt1[k*64 + j0];
            *(float4*)&wv[4] = *(const float4*)&wt1[k*64 + j0 + 4];
            #pragma unroll
            for (int i=0;i<4;i++)
                #pragma unroll
                for (int j=0;j<8;j++) acc[i][j] = fmaf(xv[i], wv[j], acc[i][j]);
        }
        float bj[8];
        #pragma unroll
        for (int j=0;j<8;j++) bj[j] = ldin(b1v, j0+j, f32);
        float s1 = 0.f, s2 = 0.f;
        #pragma unroll
        for (int i=0;i<4;i++)
            #pragma unroll
            for (int j=0;j<8;j++){
                float a2 = acc[i][j] + bj[j];
                acc[i][j] = a2; s1 += a2; s2 = fmaf(a2, a2, s2);
            }
        #pragma unroll
        for (int off = 32; off > 0; off >>= 1){
            s1 += __shfl_down(s1, off);
            s2 += __shfl_down(s2, off);
        }
        s1 = __shfl(s1, 0); s2 = __shfl(s2, 0);
        float m  = s1 / 2048.f;
        float vv = s2 / 2048.f - m*m;
        float rs = rsqrtf(vv + 1e-5f);
        float gv = ldin(g1, n, f32), bv = ldin(bb1, n, f32);
        #pragma unroll
        for (int i=0;i<4;i++)
            #pragma unroll
            for (int j=0;j<8;j++)
                cst[w][(j0+j)*36 + b0+i] =
                    fmaxf(fmaf(gv*(acc[i][j]-m), rs, bv), 0.f);
    }
    __syncthreads();

    // ---- layer 2: K=64, O=128.  lane -> b0=(lane%4)*8, j0=(lane/4)*8 ----
    {
        int b0 = (lane & 3)*8, j0 = (lane >> 2)*8;
        float acc[8][8];
        #pragma unroll
        for (int i=0;i<8;i++)
            #pragma unroll
            for (int j=0;j<8;j++) acc[i][j] = 0.f;
        for (int k = 0; k < 64; k++){
            float xv[8], wv[8];
            *(float4*)&xv[0] = *(const float4*)&cst[w][k*36 + b0];
            *(float4*)&xv[4] = *(const float4*)&cst[w][k*36 + b0 + 4];
            *(float4*)&wv[0] = *(const float4*)&wt2[k*128 + j0];
            *(float4*)&wv[4] = *(const float4*)&wt2[k*128 + j0 + 4];
            #pragma unroll
            for (int i=0;i<8;i++)
                #pragma unroll
                for (int j=0;j<8;j++) acc[i][j] = fmaf(xv[i], wv[j], acc[i][j]);
        }
        float bj[8];
        #pragma unroll
        for (int j=0;j<8;j++) bj[j] = ldin(b2v, j0+j, f32);
        float s1 = 0.f, s2 = 0.f;
        #pragma unroll
        for (int i=0;i<8;i++)
            #pragma unroll
            for (int j=0;j<8;j++){
                float a2 = acc[i][j] + bj[j];
                acc[i][j] = a2; s1 += a2; s2 = fmaf(a2, a2, s2);
            }
        #pragma unroll
        for (int off = 32; off > 0; off >>= 1){
            s1 += __shfl_down(s1, off);
            s2 += __shfl_down(s2, off);
        }
        s1 = __shfl(s1, 0); s2 = __shfl(s2, 0);
        float m  = s1 / 4096.f;
        float vv = s2 / 4096.f - m*m;
        float rs = rsqrtf(vv + 1e-5f);
        float gv = ldin(g2, n, f32), bv = ldin(bb2, n, f32);
        #pragma unroll
        for (int i=0;i<8;i++){
            union { uint4 u; ushort_t s[8]; } pk;
            #pragma unroll
            for (int j=0;j<8;j++)
                pk.s[j] = f2bf(fmaxf(fmaf(gv*(acc[i][j]-m), rs, bv), 0.f));
            *(uint4*)(out + ((size_t)(b0+i)*NN + n)*128 + j0) = pk.u;
        }
    }
}

// ---------------- merged: decoder lin+BN+ReLU (128->64) + dec tail ---------
__global__ __launch_bounds__(128) void k_dectail(
    const ushort_t* __restrict__ xin,          // A [32768][128] bf16
    const float* __restrict__ W1t,             // [128][64] (d1 transposed)
    const void* __restrict__ d1b, const void* __restrict__ bng,
    const void* __restrict__ bnb,
    const float* __restrict__ W2t,             // [64][32]
    const void* __restrict__ b2,
    const float* __restrict__ Wct, const void* __restrict__ bcb,
    const float* __restrict__ Wgt, const void* __restrict__ bgb,
    void* __restrict__ out, const void* __restrict__ detin)
{
    __shared__ __align__(16) float smem[8192 + 9216];   // 69.6 KB
    float* wt  = smem;            // [128][64] d1 weights; later dec weights
    float* xst = smem + 8192;     // [2][128*36] inputs; later cst/hs
    int f32 = detect_dev(detin);
    int t = threadIdx.x;
    int w = t >> 6, lane = t & 63;
    int n = blockIdx.x*2 + w;

    for (int i = t; i < 8192/4; i += 128)
        ((float4*)wt)[i] = ((const float4*)W1t)[i];
    float* xw = xst + w*4608;
    for (int i = lane; i < 32*16; i += 64){
        int b = i >> 4, g = i & 15;
        float f[8];
        uint4 v = *(const uint4*)(xin + ((size_t)b*NN + n)*128 + (size_t)g*8);
        unpack8(v, f);
        #pragma unroll
        for (int j=0;j<8;j++) xw[(g*8+j)*36 + b] = f[j];
    }
    __syncthreads();

    // ---- d1 GEMM (K=128, O=64) + BN stats ----
    int b0 = (lane & 7)*4, j0 = (lane >> 3)*8;
    float acc[4][8];
    #pragma unroll
    for (int i=0;i<4;i++)
        #pragma unroll
        for (int j=0;j<8;j++) acc[i][j] = 0.f;
    for (int k = 0; k < 128; k++){
        float xv[4], wv[8];
        *(float4*)&xv[0] = *(const float4*)&xw[k*36 + b0];
        *(float4*)&wv[0] = *(const float4*)&wt[k*64 + j0];
        *(float4*)&wv[4] = *(const float4*)&wt[k*64 + j0 + 4];
        #pragma unroll
        for (int i=0;i<4;i++)
            #pragma unroll
            for (int j=0;j<8;j++) acc[i][j] = fmaf(xv[i], wv[j], acc[i][j]);
    }
    float bj[8];
    #pragma unroll
    for (int j=0;j<8;j++) bj[j] = ldin(d1b, j0+j, f32);
    float s1 = 0.f, s2 = 0.f;
    #pragma unroll
    for (int i=0;i<4;i++)
        #pragma unroll
        for (int j=0;j<8;j++){
            float a2 = acc[i][j] + bj[j];
            acc[i][j] = a2; s1 += a2; s2 = fmaf(a2, a2, s2);
        }
    #pragma unroll
    for (int off = 32; off > 0; off >>= 1){
        s1 += __shfl_down(s1, off);
        s2 += __shfl_down(s2, off);
    }
    s1 = __shfl(s1, 0); s2 = __shfl(s2, 0);
    float m  = s1 / 2048.f;
    float vv = s2 / 2048.f - m*m;
    float rs = rsqrtf(vv + 1e-5f);
    float gv = ldin(bng, n, f32), bv = ldin(bnb, n, f32);
    __syncthreads();                 // wt / xst reads complete

    // ---- overlay: dec weights into wt region, cst/hs into xst region ----
    float* w2s  = wt;                // 2048 f
    float* wcs  = wt + 2048;         // 896 f
    float* wgs  = wt + 2944;         // 128 f
    float* cstw = xst + w*2080;      // [32][65] per wave
    float* hsw  = xst + 4160 + w*1056;   // [32][33] per wave
    for (int i = t; i < 512; i += 128) ((float4*)w2s)[i] = ((const float4*)W2t)[i];
    for (int i = t; i < 224; i += 128) ((float4*)wcs)[i] = ((const float4*)Wct)[i];
    if (t < 32) ((float4*)wgs)[t] = ((const float4*)Wgt)[t];
    #pragma unroll
    for (int i=0;i<4;i++)
        #pragma unroll
        for (int j=0;j<8;j++){
            float val = fmaxf(fmaf(gv*(acc[i][j]-m), rs, bv), 0.f);
            cstw[(b0+i)*65 + (j0+j)] = bf2f(f2bf(val));   // Cdec-exact rounding
        }
    __syncthreads();

    // ---- dec tail: lane -> (b = lane&31, jg = lane>>5) ----
    int b = lane & 31, jg = lane >> 5;
    float h[16];
    #pragma unroll
    for (int jj=0;jj<16;jj++) h[jj] = ldin(b2, jg*16+jj, f32);
    for (int k = 0; k < 64; k++){
        float xv = cstw[b*65 + k];
        #pragma unroll
        for (int jj=0;jj<16;jj++)
            h[jj] = fmaf(xv, w2s[k*32 + jg*16 + jj], h[jj]);
    }
    #pragma unroll
    for (int jj=0;jj<16;jj++) hsw[b*33 + jg*16 + jj] = fmaxf(h[jj], 0.f);
    __syncthreads();
    #pragma unroll
    for (int jj=0;jj<16;jj++){
        int j2 = jg*16 + jj;
        float o;
        if (j2 < 28){
            o = ldin(bcb, j2, f32);
            #pragma unroll
            for (int k=0;k<32;k++) o = fmaf(hsw[b*33 + k], wcs[k*28 + j2], o);
        } else {
            int gg = j2 - 28;
            o = ldin(bgb, gg, f32);
            #pragma unroll
            for (int k=0;k<32;k++) o = fmaf(hsw[b*33 + k], wgs[k*4 + gg], o);
        }
        size_t oi = ((size_t)b*NN + n)*32 + j2;
        if (f32) ((float*)out)[oi] = o;
        else     ((ushort_t*)out)[oi] = f2bf(o);
    }
}

// ---------------- shared tails for the fused MFMA kernels (64-row) ---------
__device__ __forceinline__ void tail_stage_x(ushort_t* xs, ushort_t* xt,
                                             const float o[2][16],
                                             int w, int col, int quad){
    #pragma unroll
    for (int nt=0;nt<2;nt++){
        int n = w*32 + nt*16 + col;
        #pragma unroll
        for (int m=0;m<4;m++){
            union { uint2 u2; ushort_t s[4]; } pk;
            #pragma unroll
            for (int reg=0;reg<4;reg++){
                int r = m*16 + quad*4 + reg;
                ushort_t hv = f2bf(o[nt][m*4+reg]);
                xs[((n>>3)*64 + r)*8 + (n&7)] = hv;
                pk.s[reg] = hv;
            }
            *(uint2*)&xt[n*XSTRIDE + m*16 + quad*4] = pk.u2;
        }
    }
}

__device__ __forceinline__ void tail_write_A(const ushort_t* xs, ushort_t* A,
                                             size_t row0, int t){
    uint4* dst = (uint4*)(A + row0*128);
    #pragma unroll
    for (int c = 0; c < 4; c++){
        int i = t + c*256;
        int r = i >> 4, kg = i & 15;
        dst[i] = *(const uint4*)&xs[(kg*64 + r)*8];
    }
}

// 128x128 MFMA with hi/lo-split B operand (B layout: [(kg*128 + n)*8]).
__device__ __forceinline__ void mfma_hilo(const ushort_t* xs,
    const ushort_t* Bh, const ushort_t* Bl, v4f acc[4][2],
    int w, int col, int quad)
{
    #pragma unroll
    for (int m=0;m<4;m++)
        #pragma unroll
        for (int nt=0;nt<2;nt++) acc[m][nt] = (v4f){0.f,0.f,0.f,0.f};
    #pragma unroll
    for (int kt = 0; kt < 4; kt++){
        int kg = kt*4 + quad;
        v8s a[4], bh[2], bl[2];
        #pragma unroll
        for (int nt=0;nt<2;nt++){
            int n = w*32 + nt*16 + col;
            bh[nt] = *(const v8s*)&Bh[(kg*128 + n)*8];
            bl[nt] = *(const v8s*)&Bl[(kg*128 + n)*8];
        }
        #pragma unroll
        for (int m=0;m<4;m++)
            a[m] = *(const v8s*)&xs[(kg*64 + m*16 + col)*8];
        #pragma unroll
        for (int m=0;m<4;m++)
            #pragma unroll
            for (int nt=0;nt<2;nt++){
                acc[m][nt] = MFMA_BF16(a[m], bh[nt], acc[m][nt], 0, 0, 0);
                acc[m][nt] = MFMA_BF16(a[m], bl[nt], acc[m][nt], 0, 0, 0);
            }
    }
}

// next linear: U = relu(x'·W^T + b) -> xs [n][XSTRIDE]; then the block's
// 64-row T-partial  Tp[s][b][c][n] (bf16) = sum_r u[r][n] * x'[r][c].
__device__ __forceinline__ void tail_lin_relu_T(ushort_t* xs, ushort_t* xt,
    const ushort_t* Whi, const ushort_t* Wlo, const void* bias,
    ushort_t* Tp, size_t row0, int t, int w, int col, int quad, int f32)
{
    v4f acc[4][2];
    mfma_hilo(xs, Whi, Wlo, acc, w, col, quad);
    float u[2][16];
    #pragma unroll
    for (int nt=0;nt<2;nt++){
        int n = w*32 + nt*16 + col;
        float bn = ldin(bias, n, f32);
        #pragma unroll
        for (int m=0;m<4;m++)
            #pragma unroll
            for (int reg=0;reg<4;reg++)
                u[nt][m*4+reg] = fmaxf(acc[m][nt][reg] + bn, 0.f);
    }
    __syncthreads();           // xs A-frag reads done
    #pragma unroll
    for (int nt=0;nt<2;nt++){
        int n = w*32 + nt*16 + col;
        #pragma unroll
        for (int m=0;m<4;m++){
            union { uint2 u2; ushort_t s[4]; } pk;
            #pragma unroll
            for (int reg=0;reg<4;reg++)
                pk.s[reg] = f2bf(u[nt][m*4+reg]);
            *(uint2*)&xs[n*XSTRIDE + m*16 + quad*4] = pk.u2;  // u in [n][72r]
        }
    }
    __syncthreads();
    v4f tacc[4][4];
    #pragma unroll
    for (int m=0;m<4;m++)
        #pragma unroll
        for (int q=0;q<4;q++) tacc[m][q] = (v4f){0.f,0.f,0.f,0.f};
    int wn = (w & 1)*64, wc = (w >> 1)*64;
    #pragma unroll
    for (int kt = 0; kt < 2; kt++){
        int kg = kt*4 + quad;
        v8s a[4], bb[4];
        #pragma unroll
        for (int m=0;m<4;m++)
            a[m] = *(const v8s*)&xs[(wn + m*16 + col)*XSTRIDE + kg*8];
        #pragma unroll
        for (int q=0;q<4;q++)
            bb[q] = *(const v8s*)&xt[(wc + q*16 + col)*XSTRIDE + kg*8];
        #pragma unroll
        for (int m=0;m<4;m++)
            #pragma unroll
            for (int q=0;q<4;q++)
                tacc[m][q] = MFMA_BF16(a[m], bb[q], tacc[m][q], 0, 0, 0);
    }
    int s16 = (int)((row0 >> 6) & 15);
    int b   = (int)(row0 >> 10);
    ushort_t* dst = Tp + ((size_t)(s16*NB + b) << 14);   // [c][n] bf16
    #pragma unroll
    for (int m=0;m<4;m++)
        #pragma unroll
        for (int q=0;q<4;q++){
            int c = wc + q*16 + col;
            union { uint2 u2; ushort_t s[4]; } pk;
            #pragma unroll
            for (int reg=0;reg<4;reg++)
                pk.s[reg] = f2bf(tacc[m][q][reg]);       // n-consecutive
            *(uint2*)&dst[c*128 + wn + m*16 + quad*4] = pk.u2;
        }
}

// ---------------- fused: enc3 sigmoid + relation-1 U + T-partial -----------
__global__ __launch_bounds__(256) void k_linfuse0(
    const ushort_t* __restrict__ xin,                 // E2, row-major
    const ushort_t* __restrict__ W3h, const ushort_t* __restrict__ W3l,
    const void* __restrict__ b3,
    const ushort_t* __restrict__ W1h, const ushort_t* __restrict__ W1l,
    const void* __restrict__ b1,
    ushort_t* __restrict__ A, ushort_t* __restrict__ Tp,
    const void* __restrict__ detin)
{
    __shared__ __align__(16) ushort_t xs[128*XSTRIDE];
    __shared__ __align__(16) ushort_t xt[128*XSTRIDE];
    int f32 = detect_dev(detin);
    int t = threadIdx.x;
    size_t row0 = (size_t)blockIdx.x * 64;
    {
        const uint4* src = (const uint4*)(xin + row0*128);
        #pragma unroll
        for (int c = 0; c < 4; c++){
            int i = t + c*256;
            int r = i >> 4, kg = i & 15;
            *(uint4*)&xs[(kg*64 + r)*8] = src[i];
        }
    }
    __syncthreads();
    int w = t >> 6, lane = t & 63;
    int col = lane & 15, quad = lane >> 4;
    v4f acc[4][2];
    mfma_hilo(xs, W3h, W3l, acc, w, col, quad);
    float o[2][16];
    #pragma unroll
    for (int nt=0;nt<2;nt++){
        int n = w*32 + nt*16 + col;
        float bn = ldin(b3, n, f32);
        #pragma unroll
        for (int m=0;m<4;m++)
            #pragma unroll
            for (int reg=0;reg<4;reg++){
                float v = acc[m][nt][reg] + bn;
                o[nt][m*4+reg] = 1.f/(1.f+expf(-v));
            }
    }
    __syncthreads();
    tail_stage_x(xs, xt, o, w, col, quad);
    __syncthreads();
    tail_write_A(xs, A, row0, t);
    tail_lin_relu_T(xs, xt, W1h, W1l, b1, Tp, row0, t, w, col, quad, f32);
}

// ---------------- reduce 16 bf16 partials -> Tt hi/lo (MFMA-B layout) ------
__global__ __launch_bounds__(256) void k_tredb(const ushort_t* __restrict__ Tp,
                                               ushort_t* __restrict__ Thi, ushort_t* __restrict__ Tlo){
    int tau = blockIdx.x*256 + threadIdx.x;     // 65536 total
    int b = tau >> 11;
    int j2 = tau & 2047;
    int cg = j2 >> 7, n = j2 & 127;
    float sum[8] = {0,0,0,0,0,0,0,0};
    #pragma unroll
    for (int s = 0; s < 16; s++){
        const ushort_t* src = Tp + ((size_t)(s*NB + b) << 14) + cg*8*128 + n;
        #pragma unroll
        for (int cc = 0; cc < 8; cc++)
            sum[cc] += bf2f(src[cc*128]);
    }
    union { uint4 u; ushort_t s[8]; } ph, pl;
    #pragma unroll
    for (int cc = 0; cc < 8; cc++){
        ushort_t h = f2bf(sum[cc]);
        ph.s[cc] = h;
        pl.s[cc] = f2bf(sum[cc] - bf2f(h));
    }
    size_t di = ((size_t)b << 14) + ((size_t)cg*128 + n)*8;
    *(uint4*)&Thi[di] = ph.u;
    *(uint4*)&Tlo[di] = pl.u;
}

// ---------------- fused: relout_r (+ lin_{r+1} + T-partial unless LAST) ----
template<int LAST>
__global__ __launch_bounds__(256) void k_relfuse(
    ushort_t* __restrict__ x,
    const ushort_t* __restrict__ Thi, const ushort_t* __restrict__ Tlo,
    const void* __restrict__ psi, const void* __restrict__ phi, const void* __restrict__ wr,
    const ushort_t* __restrict__ Wrh, const ushort_t* __restrict__ Wrl,
    const void* __restrict__ rbias,
    const ushort_t* __restrict__ Wnh, const ushort_t* __restrict__ Wnl,
    const void* __restrict__ bnext, ushort_t* __restrict__ Tp,
    const void* __restrict__ detin)
{
    __shared__ __align__(16) ushort_t xs[128*XSTRIDE];
    __shared__ __align__(16) ushort_t xt[128*XSTRIDE];
    __shared__ __align__(16) float sdvec[64];
    int f32 = detect_dev(detin);
    int t = threadIdx.x;
    size_t row0 = (size_t)blockIdx.x * 64;
    int b = (int)(row0 >> 10);
    {
        const uint4* src = (const uint4*)(x + row0*128);
        #pragma unroll
        for (int c = 0; c < 4; c++){
            int i = t + c*256;
            int r = i >> 4, kg = i & 15;
            *(uint4*)&xs[(kg*64 + r)*8] = src[i];
        }
    }
    __syncthreads();
    int w = t >> 6, lane = t & 63;
    int col = lane & 15, quad = lane >> 4;

    // ---- head: recompute sdvec = |x'_row|^2 and u = relu(W_r x' + b_r) ----
    if (t < 64){
        float s = 0.f;
        #pragma unroll 8
        for (int k=0;k<128;k++){
            float v = bf2f(xs[((k>>3)*64 + t)*8 + (k&7)]);
            s = fmaf(v, v, s);
        }
        sdvec[t] = s;
    }
    {
        v4f uacc[4][2];
        mfma_hilo(xs, Wrh, Wrl, uacc, w, col, quad);
        #pragma unroll
        for (int nt=0;nt<2;nt++){
            int n = w*32 + nt*16 + col;
            float bn = ldin(rbias, n, f32);
            #pragma unroll
            for (int m=0;m<4;m++){
                union { uint2 u2; ushort_t s[4]; } pk;
                #pragma unroll
                for (int reg=0;reg<4;reg++)
                    pk.s[reg] = f2bf(fmaxf(uacc[m][nt][reg] + bn, 0.f));
                *(uint2*)&xt[n*XSTRIDE + m*16 + quad*4] = pk.u2;  // u [n][72r]
            }
        }
    }
    __syncthreads();           // u + sdvec ready

    float alpha = ldin(wr,0,f32) * ldin(psi,0,f32) * ldin(phi,0,f32) * (1.f/1024.f);
    const ushort_t* sh = Thi + ((size_t)b << 14);
    const ushort_t* sl = Tlo + ((size_t)b << 14);
    v4f acc[4][2];
    mfma_hilo(xs, sh, sl, acc, w, col, quad);
    float o[2][16];
    #pragma unroll
    for (int m=0;m<4;m++){
        float4 d4 = *(const float4*)&sdvec[m*16 + quad*4];
        const float* dr = (const float*)&d4;
        #pragma unroll
        for (int nt=0;nt<2;nt++){
            int n = w*32 + nt*16 + col;
            #pragma unroll
            for (int reg=0;reg<4;reg++){
                int r = m*16 + quad*4 + reg;
                float ufv = bf2f(xt[n*XSTRIDE + r]);     // u (recomputed)
                float xv = bf2f(xs[((n>>3)*64 + r)*8 + (n&7)]);
                o[nt][m*4+reg] = fmaf(alpha, acc[m][nt][reg] - dr[reg]*ufv, xv);
            }
        }
    }
    __syncthreads();           // all xs / xt / sdvec reads done
    tail_stage_x(xs, xt, o, w, col, quad);
    __syncthreads();
    tail_write_A(xs, x, row0, t);
    if (!LAST)
        tail_lin_relu_T(xs, xt, Wnh, Wnl, bnext, Tp,
                        row0, t, w, col, quad, f32);
}

// ---------------------------------------------------------------------------
enum { O_E1=0, O_E2=2048, O_D1=10240, O_D2=18432, O_BC=20480, O_BG=21376 };

extern "C" void kernel_launch(void* const* d_in, const int* in_sizes, int n_in,
                              void* d_out, int out_size, void* d_ws, size_t ws_size,
                              hipStream_t stream)
{
    (void)in_sizes; (void)n_in; (void)out_size; (void)ws_size;
    const void* input = d_in[0];
    const void* e1_W = d_in[1];  const void* e1_b = d_in[2];
    const void* bn1_g = d_in[3]; const void* bn1_b = d_in[4];
    const void* e2_W = d_in[5];  const void* e2_b = d_in[6];
    const void* bn2_g = d_in[7]; const void* bn2_b = d_in[8];
    const void* e3_W = d_in[9];  const void* e3_b = d_in[10];
    const void *rW[4], *rb[4], *rpsi[4], *rphi[4], *rwr[4];
    for (int r = 0; r < 4; r++){
        rW[r]   = d_in[11 + r*5 + 0];
        rb[r]   = d_in[11 + r*5 + 1];
        rpsi[r] = d_in[11 + r*5 + 2];
        rphi[r] = d_in[11 + r*5 + 3];
        rwr[r]  = d_in[11 + r*5 + 4];
    }
    const void* d1_W = d_in[31]; const void* d1_b = d_in[32];
    const void* dbn_g = d_in[33];const void* dbn_b = d_in[34];
    const void* d2_W = d_in[35]; const void* d2_b = d_in[36];
    const void* bc_W = d_in[37]; const void* bc_b = d_in[38];
    const void* bg_W = d_in[39]; const void* bg_b = d_in[40];

    // ---- workspace layout, float offsets (all 16B-aligned) ----
    float*    ws_f = (float*)d_ws;
    float*    wpf  = ws_f;                          // 21504 f
    ushort_t* whi  = (ushort_t*)(ws_f + 54272);     // 5*16384 us
    ushort_t* wlo  = (ushort_t*)(ws_f + 95232);     // 5*16384 us
    ushort_t* Thi  = (ushort_t*)(ws_f + 136192);    // 524288 us
    ushort_t* Tlo  = (ushort_t*)(ws_f + 398336);    // 524288 us
    ushort_t* Tp   = (ushort_t*)(ws_f + 660480);    // 16*32*16384 us (bf16)
    ushort_t* A    = (ushort_t*)(ws_f + 4854784);   // [32768][128] bf16
    ushort_t* E2   = (ushort_t*)(ws_f + 9049088);   // [32768][128] bf16

    PrepArgs pa;
    const void* srcs[9] = {d1_W, d2_W, bc_W, bg_W,
                           e3_W, rW[0], rW[1], rW[2], rW[3]};
    const int  Ks[9]   = {128,64,32,32, 128,128,128,128,128};
    const int  Os[9]   = {64,32,28,4,   128,128,128,128,128};
    const int  offs[9] = {O_D1,O_D2,O_BC,O_BG, 0,0,0,0,0};
    for (int i=0;i<9;i++){ pa.w[i]=srcs[i]; pa.K[i]=Ks[i]; pa.O[i]=Os[i]; pa.off[i]=offs[i]; }

    k_enc0<<<512, 128, 0, stream>>>(pa, wpf, whi, wlo,
                                    input, e1_W, e1_b, bn1_g, bn1_b,
                                    e2_W, e2_b, bn2_g, bn2_b,
                                    E2, input);
    k_linfuse0<<<512, 256, 0, stream>>>(E2, whi, wlo, e3_b,
                                        whi + 16384, wlo + 16384, rb[0],
                                        A, Tp, input);

    for (int r = 0; r < 4; r++){
        k_tredb<<<256, 256, 0, stream>>>(Tp, Thi, Tlo);
        if (r < 3)
            k_relfuse<0><<<512, 256, 0, stream>>>(A, Thi, Tlo,
                rpsi[r], rphi[r], rwr[r],
                whi + (size_t)(1+r)*16384, wlo + (size_t)(1+r)*16384, rb[r],
                whi + (size_t)(2+r)*16384, wlo + (size_t)(2+r)*16384, rb[r+1],
                Tp, input);
        else
            k_relfuse<1><<<512, 256, 0, stream>>>(A, Thi, Tlo,
                rpsi[r], rphi[r], rwr[r],
                whi + (size_t)4*16384, wlo + (size_t)4*16384, rb[3],
                whi, wlo, rb[0],
                Tp, input);
    }

    k_dectail<<<512, 128, 0, stream>>>(A, wpf+O_D1, d1_b, dbn_g, dbn_b,
                                       wpf+O_D2, d2_b, wpf+O_BC, bc_b,
                                       wpf+O_BG, bg_b, d_out, input);
}